// Round 1
// baseline (710.458 us; speedup 1.0000x reference)
//
#include <hip/hip_runtime.h>
#include <stdint.h>

using u16 = unsigned short;
typedef __attribute__((ext_vector_type(8))) short bf16x8;
typedef __attribute__((ext_vector_type(4))) float f32x4;

constexpr int D  = 512;
constexpr int P  = 256;
constexpr int BM = 64;
constexpr int XS = D + 8;   // ushort stride for x tile  (1040 B/row, 16B aligned, bank-offset 4)
constexpr int ZS = P + 4;   // float stride for z tile   (1040 B/row) — aliases XS region exactly
constexpr int WS = P + 8;   // ushort stride for w/gated (528 B/row)

__device__ __forceinline__ u16 f2bf(float f) {  // RNE float->bf16
  uint32_t u = __builtin_bit_cast(uint32_t, f);
  u += 0x7fffu + ((u >> 16) & 1u);
  return (u16)(u >> 16);
}

// ---------------- prep kernels ----------------

__global__ void k_gate(const float* __restrict__ gl, const float* __restrict__ traw,
                       float* __restrict__ gate) {
  int l = threadIdx.x;  // 64 threads
  float t = 1.f / (1.f + expf(-traw[0]));
  t = t * (1.f - 0.001f) + 0.001f;
  float v[4];
  float m = -3.4e38f;
  #pragma unroll
  for (int i = 0; i < 4; ++i) { v[i] = gl[l + i * 64] / t; m = fmaxf(m, v[i]); }
  #pragma unroll
  for (int s = 1; s < 64; s <<= 1) m = fmaxf(m, __shfl_xor(m, s));
  float sum = 0.f;
  #pragma unroll
  for (int i = 0; i < 4; ++i) { v[i] = expf(v[i] - m); sum += v[i]; }
  #pragma unroll
  for (int s = 1; s < 64; s <<= 1) sum += __shfl_xor(sum, s);
  #pragma unroll
  for (int i = 0; i < 4; ++i) gate[l + i * 64] = v[i] / sum;
}

// entmax15 over each row of adj_logits; writes E_gT[j][k] = E[k][j]*gate[j] in bf16
__global__ void k_adj(const float* __restrict__ adj, const float* __restrict__ gate,
                      u16* __restrict__ EgT) {
  int k = blockIdx.x, l = threadIdx.x;  // 256 blocks x 64 threads
  float z[4];
  float m = -3.4e38f;
  #pragma unroll
  for (int i = 0; i < 4; ++i) { z[i] = adj[(size_t)k * P + l + i * 64] * 0.5f; m = fmaxf(m, z[i]); }
  #pragma unroll
  for (int s = 1; s < 64; s <<= 1) m = fmaxf(m, __shfl_xor(m, s));
  float lo = m - 1.f, hi = m;
  for (int it = 0; it < 26; ++it) {
    float tau = 0.5f * (lo + hi), s = 0.f;
    #pragma unroll
    for (int i = 0; i < 4; ++i) { float d = z[i] - tau; s += (d > 0.f) ? d * d : 0.f; }
    #pragma unroll
    for (int sh = 1; sh < 64; sh <<= 1) s += __shfl_xor(s, sh);
    if (s >= 1.f) lo = tau; else hi = tau;
  }
  float tau = 0.5f * (lo + hi);
  #pragma unroll
  for (int i = 0; i < 4; ++i) {
    int j = l + i * 64;
    float d = z[i] - tau;
    float p = (d > 0.f) ? d * d : 0.f;
    EgT[(size_t)j * P + k] = f2bf(p * gate[j]);
  }
}

// proto -> bf16 row-major [P][D] and transposed [D][P]; pnorm[p] = ||proto_p||^2 (fp32)
__global__ void k_proto(const float* __restrict__ proto, u16* __restrict__ pb,
                        u16* __restrict__ pbT, float* __restrict__ pnorm) {
  int p = blockIdx.x, t = threadIdx.x;  // 256 blocks x 256 threads
  float s = 0.f;
  for (int d = t; d < D; d += 256) {
    float v = proto[(size_t)p * D + d];
    s += v * v;
    u16 u = f2bf(v);
    pb[(size_t)p * D + d]  = u;
    pbT[(size_t)d * P + p] = u;
  }
  #pragma unroll
  for (int sh = 1; sh < 64; sh <<= 1) s += __shfl_xor(s, sh);
  __shared__ float red[4];
  if ((t & 63) == 0) red[t >> 6] = s;
  __syncthreads();
  if (t == 0) pnorm[p] = red[0] + red[1] + red[2] + red[3];
}

// ---------------- fused main kernel ----------------

__global__ __launch_bounds__(256)
void k_main(const float* __restrict__ x, const u16* __restrict__ pb,
            const u16* __restrict__ pbT, const u16* __restrict__ EgT,
            const float* __restrict__ pnorm,
            float* __restrict__ out_blend, float* __restrict__ out_gated) {
  __shared__ __align__(16) char regA[BM * XS * 2];   // 66560 B: x_bf16 -> z_f32 -> gated_bf16
  __shared__ __align__(16) u16 wbuf[BM][WS];         // 33792 B: entmax weights (bf16)
  __shared__ float pnS[P];
  __shared__ float xnS[BM];

  auto xs  = (u16 (*)[XS])regA;
  auto zsp = (float (*)[ZS])regA;
  auto gs  = (u16 (*)[WS])regA;

  int tid  = threadIdx.x;
  int brow = blockIdx.x * BM;

  pnS[tid] = pnorm[tid];   // blockDim == P == 256

  // ---- stage x tile as bf16, compute ||x||^2 in fp32 ----
  {
    int r = tid >> 2, q = tid & 3;
    const float* xr = x + (size_t)(brow + r) * D + q * 128;
    float s = 0.f;
    for (int i = 0; i < 128; i += 4) {
      float4 v = *(const float4*)(xr + i);
      s += v.x * v.x + v.y * v.y + v.z * v.z + v.w * v.w;
      uint2 pk;
      pk.x = (uint32_t)f2bf(v.x) | ((uint32_t)f2bf(v.y) << 16);
      pk.y = (uint32_t)f2bf(v.z) | ((uint32_t)f2bf(v.w) << 16);
      *(uint2*)&xs[r][q * 128 + i] = pk;
    }
    s += __shfl_xor(s, 1);
    s += __shfl_xor(s, 2);
    if (q == 0) xnS[r] = s;
  }
  __syncthreads();

  int l    = tid & 63;
  int wv   = tid >> 6;        // wave id, 4 waves x 16-row stripes
  int r0   = wv * 16;
  int lrow = l & 15;
  int lk   = (l >> 4) * 8;
  int lr4  = (l >> 4) * 4;

  // ---- GEMM1: dot[64][256] = x_bf16 @ proto^T ----
  f32x4 acc[16];
  #pragma unroll
  for (int c = 0; c < 16; ++c) acc[c] = {0.f, 0.f, 0.f, 0.f};

  for (int kk = 0; kk < D; kk += 32) {
    bf16x8 a = *(const bf16x8*)&xs[r0 + lrow][kk + lk];
    #pragma unroll
    for (int c = 0; c < 16; ++c) {
      bf16x8 b = *(const bf16x8*)(pb + (size_t)(c * 16 + lrow) * D + kk + lk);
      acc[c] = __builtin_amdgcn_mfma_f32_16x16x32_bf16(a, b, acc[c], 0, 0, 0);
    }
  }
  __syncthreads();  // xs dead; regA becomes z

  // ---- z = -0.5*sqrt(clip(xn - 2*dot + pn, 0)) ----
  #pragma unroll
  for (int c = 0; c < 16; ++c) {
    int col = c * 16 + lrow;
    float pn = pnS[col];
    #pragma unroll
    for (int j = 0; j < 4; ++j) {
      int row = r0 + lr4 + j;
      float sq = xnS[row] - 2.f * acc[c][j] + pn;
      zsp[row][col] = -0.5f * sqrtf(fmaxf(sq, 0.f));
    }
  }
  __syncthreads();

  // ---- entmax15 per row: bisection on f(tau)=sum(max(z-tau,0)^2)=1 ----
  {
    int r = tid >> 2, q = tid & 3;  // 4 threads per row, 64 elements each (in VGPRs)
    const float4* z4 = (const float4*)(&zsp[r][q * 64]);
    float4 zq[16];
    #pragma unroll
    for (int i = 0; i < 16; ++i) zq[i] = z4[i];
    float m = -3.4e38f;
    #pragma unroll
    for (int i = 0; i < 16; ++i)
      m = fmaxf(m, fmaxf(fmaxf(zq[i].x, zq[i].y), fmaxf(zq[i].z, zq[i].w)));
    m = fmaxf(m, __shfl_xor(m, 1));
    m = fmaxf(m, __shfl_xor(m, 2));
    float lo = m - 1.f, hi = m;
    for (int it = 0; it < 22; ++it) {
      float tau = 0.5f * (lo + hi), s = 0.f;
      #pragma unroll
      for (int i = 0; i < 16; ++i) {
        float d0 = zq[i].x - tau; s += (d0 > 0.f) ? d0 * d0 : 0.f;
        float d1 = zq[i].y - tau; s += (d1 > 0.f) ? d1 * d1 : 0.f;
        float d2 = zq[i].z - tau; s += (d2 > 0.f) ? d2 * d2 : 0.f;
        float d3 = zq[i].w - tau; s += (d3 > 0.f) ? d3 * d3 : 0.f;
      }
      s += __shfl_xor(s, 1);
      s += __shfl_xor(s, 2);
      if (s >= 1.f) lo = tau; else hi = tau;
    }
    float tau = 0.5f * (lo + hi);
    u16* wr = &wbuf[tid >> 2][q * 64];
    #pragma unroll
    for (int i = 0; i < 16; ++i) {
      float d0 = zq[i].x - tau; float w0 = (d0 > 0.f) ? d0 * d0 : 0.f;
      float d1 = zq[i].y - tau; float w1 = (d1 > 0.f) ? d1 * d1 : 0.f;
      float d2 = zq[i].z - tau; float w2 = (d2 > 0.f) ? d2 * d2 : 0.f;
      float d3 = zq[i].w - tau; float w3 = (d3 > 0.f) ? d3 * d3 : 0.f;
      uint2 pk;
      pk.x = (uint32_t)f2bf(w0) | ((uint32_t)f2bf(w1) << 16);
      pk.y = (uint32_t)f2bf(w2) | ((uint32_t)f2bf(w3) << 16);
      *(uint2*)(wr + i * 4) = pk;
    }
  }
  __syncthreads();  // wbuf ready; zs reads done (regA free for gated)

  // ---- GEMM2: routed_g[64][256] = w @ E_g ----
  f32x4 acc2[16];
  #pragma unroll
  for (int c = 0; c < 16; ++c) acc2[c] = {0.f, 0.f, 0.f, 0.f};

  for (int kk = 0; kk < P; kk += 32) {
    bf16x8 a = *(const bf16x8*)&wbuf[r0 + lrow][kk + lk];
    #pragma unroll
    for (int c = 0; c < 16; ++c) {
      bf16x8 b = *(const bf16x8*)(EgT + (size_t)(c * 16 + lrow) * P + kk + lk);
      acc2[c] = __builtin_amdgcn_mfma_f32_16x16x32_bf16(a, b, acc2[c], 0, 0, 0);
    }
  }

  // ---- row-normalize: gated = routed_g / (rowsum + 1e-8) ----
  float part[4] = {0.f, 0.f, 0.f, 0.f};
  #pragma unroll
  for (int c = 0; c < 16; ++c) {
    #pragma unroll
    for (int j = 0; j < 4; ++j) part[j] += acc2[c][j];
  }
  #pragma unroll
  for (int j = 0; j < 4; ++j) {
    part[j] += __shfl_xor(part[j], 1);
    part[j] += __shfl_xor(part[j], 2);
    part[j] += __shfl_xor(part[j], 4);
    part[j] += __shfl_xor(part[j], 8);
    part[j] = 1.f / (part[j] + 1e-8f);
  }

  #pragma unroll
  for (int c = 0; c < 16; ++c) {
    int col = c * 16 + lrow;
    #pragma unroll
    for (int j = 0; j < 4; ++j) {
      int row = r0 + lr4 + j;
      float g = acc2[c][j] * part[j];
      out_gated[(size_t)(brow + row) * P + col] = g;
      gs[row][col] = f2bf(g);
    }
  }
  __syncthreads();

  // ---- GEMM3: blended[64][512] = gated @ proto (two 256-col halves) ----
  #pragma unroll 1
  for (int half = 0; half < 2; ++half) {
    f32x4 acc3[16];
    #pragma unroll
    for (int c = 0; c < 16; ++c) acc3[c] = {0.f, 0.f, 0.f, 0.f};
    for (int kk = 0; kk < P; kk += 32) {
      bf16x8 a = *(const bf16x8*)&gs[r0 + lrow][kk + lk];
      #pragma unroll
      for (int c = 0; c < 16; ++c) {
        int dcol = half * 256 + c * 16 + lrow;
        bf16x8 b = *(const bf16x8*)(pbT + (size_t)dcol * P + kk + lk);
        acc3[c] = __builtin_amdgcn_mfma_f32_16x16x32_bf16(a, b, acc3[c], 0, 0, 0);
      }
    }
    #pragma unroll
    for (int c = 0; c < 16; ++c) {
      int dcol = half * 256 + c * 16 + lrow;
      #pragma unroll
      for (int j = 0; j < 4; ++j) {
        int row = r0 + lr4 + j;
        out_blend[(size_t)(brow + row) * D + dcol] = acc3[c][j];
      }
    }
  }
}

// ---------------- launcher ----------------

extern "C" void kernel_launch(void* const* d_in, const int* in_sizes, int n_in,
                              void* d_out, int out_size, void* d_ws, size_t ws_size,
                              hipStream_t stream) {
  const float* x     = (const float*)d_in[0];
  const float* proto = (const float*)d_in[1];
  const float* adj   = (const float*)d_in[2];
  const float* gl    = (const float*)d_in[3];
  const float* traw  = (const float*)d_in[4];
  int N = in_sizes[0] / D;  // 65536

  u16*   pb    = (u16*)d_ws;                  // [P][D] bf16 proto        (256 KB)
  u16*   pbT   = pb  + (size_t)P * D;         // [D][P] bf16 proto^T      (256 KB)
  u16*   EgT   = pbT + (size_t)D * P;         // [P][P] bf16 (E*gate)^T   (128 KB)
  float* pnorm = (float*)(EgT + (size_t)P * P);
  float* gate  = pnorm + P;

  float* out_blend = (float*)d_out;
  float* out_gated = out_blend + (size_t)N * D;

  k_gate<<<1, 64, 0, stream>>>(gl, traw, gate);
  k_proto<<<P, 256, 0, stream>>>(proto, pb, pbT, pnorm);
  k_adj<<<P, 64, 0, stream>>>(adj, gate, EgT);
  k_main<<<N / BM, 256, 0, stream>>>(x, pb, pbT, EgT, pnorm, out_blend, out_gated);
}

// Round 2
// 592.556 us; speedup vs baseline: 1.1990x; 1.1990x over previous
//
#include <hip/hip_runtime.h>
#include <stdint.h>

using u16 = unsigned short;
typedef __attribute__((ext_vector_type(8))) short bf16x8;
typedef __attribute__((ext_vector_type(4))) float f32x4;

constexpr int D  = 512;
constexpr int P  = 256;
constexpr int BM = 64;
constexpr int WS = P + 8;   // ushort stride for w/gated buffer (528 B/row -> conflict-free b128)

__device__ __forceinline__ u16 f2bf(float f) {  // RNE float->bf16
  uint32_t u = __builtin_bit_cast(uint32_t, f);
  u += 0x7fffu + ((u >> 16) & 1u);
  return (u16)(u >> 16);
}

// ---------------- prep kernels ----------------

__global__ void k_gate(const float* __restrict__ gl, const float* __restrict__ traw,
                       float* __restrict__ gate) {
  int l = threadIdx.x;  // 64 threads
  float t = 1.f / (1.f + expf(-traw[0]));
  t = t * (1.f - 0.001f) + 0.001f;
  float v[4];
  float m = -3.4e38f;
  #pragma unroll
  for (int i = 0; i < 4; ++i) { v[i] = gl[l + i * 64] / t; m = fmaxf(m, v[i]); }
  #pragma unroll
  for (int s = 1; s < 64; s <<= 1) m = fmaxf(m, __shfl_xor(m, s));
  float sum = 0.f;
  #pragma unroll
  for (int i = 0; i < 4; ++i) { v[i] = expf(v[i] - m); sum += v[i]; }
  #pragma unroll
  for (int s = 1; s < 64; s <<= 1) sum += __shfl_xor(sum, s);
  #pragma unroll
  for (int i = 0; i < 4; ++i) gate[l + i * 64] = v[i] / sum;
}

// entmax15 over each row of adj_logits; writes E_gT[j][k] = E[k][j]*gate[j] in bf16
__global__ void k_adj(const float* __restrict__ adj, const float* __restrict__ gate,
                      u16* __restrict__ EgT) {
  int k = blockIdx.x, l = threadIdx.x;  // 256 blocks x 64 threads
  float z[4];
  float m = -3.4e38f;
  #pragma unroll
  for (int i = 0; i < 4; ++i) { z[i] = adj[(size_t)k * P + l + i * 64] * 0.5f; m = fmaxf(m, z[i]); }
  #pragma unroll
  for (int s = 1; s < 64; s <<= 1) m = fmaxf(m, __shfl_xor(m, s));
  float lo = m - 1.f, hi = m;
  for (int it = 0; it < 26; ++it) {
    float tau = 0.5f * (lo + hi), s = 0.f;
    #pragma unroll
    for (int i = 0; i < 4; ++i) { float d = z[i] - tau; s += (d > 0.f) ? d * d : 0.f; }
    #pragma unroll
    for (int sh = 1; sh < 64; sh <<= 1) s += __shfl_xor(s, sh);
    if (s >= 1.f) lo = tau; else hi = tau;
  }
  float tau = 0.5f * (lo + hi);
  #pragma unroll
  for (int i = 0; i < 4; ++i) {
    int j = l + i * 64;
    float d = z[i] - tau;
    float p = (d > 0.f) ? d * d : 0.f;
    EgT[(size_t)j * P + k] = f2bf(p * gate[j]);
  }
}

// proto -> bf16 row-major [P][D] and transposed [D][P]; pnorm[p] = ||proto_p||^2 (fp32)
__global__ void k_proto(const float* __restrict__ proto, u16* __restrict__ pb,
                        u16* __restrict__ pbT, float* __restrict__ pnorm) {
  int p = blockIdx.x, t = threadIdx.x;  // 256 blocks x 256 threads
  float s = 0.f;
  for (int d = t; d < D; d += 256) {
    float v = proto[(size_t)p * D + d];
    s += v * v;
    u16 u = f2bf(v);
    pb[(size_t)p * D + d]  = u;
    pbT[(size_t)d * P + p] = u;
  }
  #pragma unroll
  for (int sh = 1; sh < 64; sh <<= 1) s += __shfl_xor(s, sh);
  __shared__ float red[4];
  if ((t & 63) == 0) red[t >> 6] = s;
  __syncthreads();
  if (t == 0) pnorm[p] = red[0] + red[1] + red[2] + red[3];
}

// ---------------- fused main kernel (zero barriers, wave-private LDS stripes) ----------------

__global__ __launch_bounds__(256, 4)
void k_main(const float* __restrict__ x, const u16* __restrict__ pb,
            const u16* __restrict__ pbT, const u16* __restrict__ EgT,
            const float* __restrict__ pnorm,
            float* __restrict__ out_blend, float* __restrict__ out_gated) {
  __shared__ __align__(16) u16 wbuf[BM][WS];   // 33792 B: entmax weights -> gated (bf16)

  int tid  = threadIdx.x;
  int brow = blockIdx.x * BM;

  int l    = tid & 63;
  int wv   = tid >> 6;        // wave id, 4 waves x 16-row stripes
  int r0   = wv * 16;
  int lrow = l & 15;
  int lk   = (l >> 4) * 8;    // k-offset within 32-wide K-step
  int lr4  = (l >> 4) * 4;    // row offset of this lane's acc quadrant

  // prototype norms for this lane's 16 output cols (hits L1/L2; issued early)
  float pn[16];
  #pragma unroll
  for (int c = 0; c < 16; ++c) pn[c] = pnorm[c * 16 + lrow];

  // ---- GEMM1: dot[64][256] = x_bf16 @ proto^T ; A streamed from global, ssq on the fly ----
  f32x4 acc[16];
  #pragma unroll
  for (int c = 0; c < 16; ++c) acc[c] = {0.f, 0.f, 0.f, 0.f};

  const float* xrow = x + (size_t)(brow + r0 + lrow) * D + lk;
  const u16*   pbB  = pb + (size_t)lrow * D + lk;
  float ssq = 0.f;

  for (int kk = 0; kk < D; kk += 32) {
    float4 v0 = *(const float4*)(xrow + kk);
    float4 v1 = *(const float4*)(xrow + kk + 4);
    ssq += v0.x * v0.x + v0.y * v0.y + v0.z * v0.z + v0.w * v0.w;
    ssq += v1.x * v1.x + v1.y * v1.y + v1.z * v1.z + v1.w * v1.w;
    union { bf16x8 v; uint32_t u[4]; } a;
    a.u[0] = (uint32_t)f2bf(v0.x) | ((uint32_t)f2bf(v0.y) << 16);
    a.u[1] = (uint32_t)f2bf(v0.z) | ((uint32_t)f2bf(v0.w) << 16);
    a.u[2] = (uint32_t)f2bf(v1.x) | ((uint32_t)f2bf(v1.y) << 16);
    a.u[3] = (uint32_t)f2bf(v1.z) | ((uint32_t)f2bf(v1.w) << 16);
    #pragma unroll
    for (int c = 0; c < 16; ++c) {
      bf16x8 b = *(const bf16x8*)(pbB + (size_t)c * 16 * D + kk);
      acc[c] = __builtin_amdgcn_mfma_f32_16x16x32_bf16(a.v, b, acc[c], 0, 0, 0);
    }
  }

  // full row ssq: union over the 4 lk-groups holding the same row
  ssq += __shfl_xor(ssq, 16);
  ssq += __shfl_xor(ssq, 32);
  // xn for this lane's 4 acc rows (rows r0+lr4+j live in lanes lr4+j)
  float xnj[4];
  #pragma unroll
  for (int j = 0; j < 4; ++j) xnj[j] = __shfl(ssq, lr4 + j);

  // ---- z = -0.5*sqrt(clip(xn - 2*dot + pn, 0)) in place ----
  #pragma unroll
  for (int c = 0; c < 16; ++c) {
    #pragma unroll
    for (int j = 0; j < 4; ++j) {
      float sq = xnj[j] - 2.f * acc[c][j] + pn[c];
      acc[c][j] = -0.5f * sqrtf(fmaxf(sq, 0.f));
    }
  }

  // ---- entmax15: bisection fully in registers (4 rows/lane, reduce over 16-lane group) ----
  float mj[4] = {-3.4e38f, -3.4e38f, -3.4e38f, -3.4e38f};
  #pragma unroll
  for (int c = 0; c < 16; ++c) {
    #pragma unroll
    for (int j = 0; j < 4; ++j) mj[j] = fmaxf(mj[j], acc[c][j]);
  }
  #pragma unroll
  for (int j = 0; j < 4; ++j) {
    mj[j] = fmaxf(mj[j], __shfl_xor(mj[j], 1));
    mj[j] = fmaxf(mj[j], __shfl_xor(mj[j], 2));
    mj[j] = fmaxf(mj[j], __shfl_xor(mj[j], 4));
    mj[j] = fmaxf(mj[j], __shfl_xor(mj[j], 8));
  }
  float lo[4], hi[4];
  #pragma unroll
  for (int j = 0; j < 4; ++j) { lo[j] = mj[j] - 1.f; hi[j] = mj[j]; }

  for (int it = 0; it < 18; ++it) {
    float tau[4], s[4];
    #pragma unroll
    for (int j = 0; j < 4; ++j) { tau[j] = 0.5f * (lo[j] + hi[j]); s[j] = 0.f; }
    #pragma unroll
    for (int c = 0; c < 16; ++c) {
      #pragma unroll
      for (int j = 0; j < 4; ++j) {
        float d = fmaxf(acc[c][j] - tau[j], 0.f);
        s[j] = fmaf(d, d, s[j]);
      }
    }
    #pragma unroll
    for (int j = 0; j < 4; ++j) {
      s[j] += __shfl_xor(s[j], 1);
      s[j] += __shfl_xor(s[j], 2);
      s[j] += __shfl_xor(s[j], 4);
      s[j] += __shfl_xor(s[j], 8);
      bool ge = (s[j] >= 1.f);
      lo[j] = ge ? tau[j] : lo[j];
      hi[j] = ge ? hi[j] : tau[j];
    }
  }

  // ---- weights -> bf16 -> LDS (wave-private stripe; layout transpose for A-frags) ----
  {
    float tau[4];
    #pragma unroll
    for (int j = 0; j < 4; ++j) tau[j] = 0.5f * (lo[j] + hi[j]);
    #pragma unroll
    for (int c = 0; c < 16; ++c) {
      #pragma unroll
      for (int j = 0; j < 4; ++j) {
        float d = fmaxf(acc[c][j] - tau[j], 0.f);
        wbuf[r0 + lr4 + j][c * 16 + lrow] = f2bf(d * d);
      }
    }
  }

  // ---- GEMM2: routed_g[64][256] = w @ E_g ----
  f32x4 acc2[16];
  #pragma unroll
  for (int c = 0; c < 16; ++c) acc2[c] = {0.f, 0.f, 0.f, 0.f};

  const u16* egB = EgT + (size_t)lrow * P + lk;
  for (int kk = 0; kk < P; kk += 32) {
    bf16x8 a = *(const bf16x8*)&wbuf[r0 + lrow][kk + lk];
    #pragma unroll
    for (int c = 0; c < 16; ++c) {
      bf16x8 b = *(const bf16x8*)(egB + (size_t)c * 16 * P + kk);
      acc2[c] = __builtin_amdgcn_mfma_f32_16x16x32_bf16(a, b, acc2[c], 0, 0, 0);
    }
  }

  // ---- row-normalize: gated = routed_g / (rowsum + 1e-8) ----
  float part[4] = {0.f, 0.f, 0.f, 0.f};
  #pragma unroll
  for (int c = 0; c < 16; ++c) {
    #pragma unroll
    for (int j = 0; j < 4; ++j) part[j] += acc2[c][j];
  }
  #pragma unroll
  for (int j = 0; j < 4; ++j) {
    part[j] += __shfl_xor(part[j], 1);
    part[j] += __shfl_xor(part[j], 2);
    part[j] += __shfl_xor(part[j], 4);
    part[j] += __shfl_xor(part[j], 8);
    part[j] = 1.f / (part[j] + 1e-8f);
  }

  #pragma unroll
  for (int c = 0; c < 16; ++c) {
    int col = c * 16 + lrow;
    #pragma unroll
    for (int j = 0; j < 4; ++j) {
      int row = r0 + lr4 + j;
      float g = acc2[c][j] * part[j];
      out_gated[(size_t)(brow + row) * P + col] = g;
      wbuf[row][col] = f2bf(g);   // same wave-private stripe; w is dead
    }
  }

  // ---- GEMM3: blended[64][512] = gated @ proto (two 256-col halves) ----
  #pragma unroll 1
  for (int half = 0; half < 2; ++half) {
    f32x4 acc3[16];
    #pragma unroll
    for (int c = 0; c < 16; ++c) acc3[c] = {0.f, 0.f, 0.f, 0.f};
    const u16* ptB = pbT + (size_t)(half * 256 + lrow) * P + lk;
    for (int kk = 0; kk < P; kk += 32) {
      bf16x8 a = *(const bf16x8*)&wbuf[r0 + lrow][kk + lk];
      #pragma unroll
      for (int c = 0; c < 16; ++c) {
        bf16x8 b = *(const bf16x8*)(ptB + (size_t)c * 16 * P + kk);
        acc3[c] = __builtin_amdgcn_mfma_f32_16x16x32_bf16(a, b, acc3[c], 0, 0, 0);
      }
    }
    #pragma unroll
    for (int c = 0; c < 16; ++c) {
      int dcol = half * 256 + c * 16 + lrow;
      #pragma unroll
      for (int j = 0; j < 4; ++j) {
        int row = r0 + lr4 + j;
        out_blend[(size_t)(brow + row) * D + dcol] = acc3[c][j];
      }
    }
  }
}

// ---------------- launcher ----------------

extern "C" void kernel_launch(void* const* d_in, const int* in_sizes, int n_in,
                              void* d_out, int out_size, void* d_ws, size_t ws_size,
                              hipStream_t stream) {
  const float* x     = (const float*)d_in[0];
  const float* proto = (const float*)d_in[1];
  const float* adj   = (const float*)d_in[2];
  const float* gl    = (const float*)d_in[3];
  const float* traw  = (const float*)d_in[4];
  int N = in_sizes[0] / D;  // 65536

  u16*   pb    = (u16*)d_ws;                  // [P][D] bf16 proto        (256 KB)
  u16*   pbT   = pb  + (size_t)P * D;         // [D][P] bf16 proto^T      (256 KB)
  u16*   EgT   = pbT + (size_t)D * P;         // [P][P] bf16 (E*gate)^T   (128 KB)
  float* pnorm = (float*)(EgT + (size_t)P * P);
  float* gate  = pnorm + P;

  float* out_blend = (float*)d_out;
  float* out_gated = out_blend + (size_t)N * D;

  k_gate<<<1, 64, 0, stream>>>(gl, traw, gate);
  k_proto<<<P, 256, 0, stream>>>(proto, pb, pbT, pnorm);
  k_adj<<<P, 64, 0, stream>>>(adj, gate, EgT);
  k_main<<<N / BM, 256, 0, stream>>>(x, pb, pbT, EgT, pnorm, out_blend, out_gated);
}

// Round 3
// 420.993 us; speedup vs baseline: 1.6876x; 1.4075x over previous
//
#include <hip/hip_runtime.h>
#include <stdint.h>

using u16 = unsigned short;
typedef __attribute__((ext_vector_type(8))) short bf16x8;
typedef __attribute__((ext_vector_type(4))) float f32x4;

constexpr int D  = 512;
constexpr int P  = 256;
constexpr int BM = 64;
constexpr int WS = P + 8;   // ushort stride for w/gated buffer (528 B/row)

__device__ __forceinline__ u16 f2bf(float f) {  // RNE float->bf16
  uint32_t u = __builtin_bit_cast(uint32_t, f);
  u += 0x7fffu + ((u >> 16) & 1u);
  return (u16)(u >> 16);
}

// Fragment-major B layouts: element (tile t, step s, lane l, e) at ((s*NT+t)*64+l)*8+e
// where lane l = g*16 + lrow holds B[col = t*16 + lrow][k = s*32 + g*8 + e].
// Every MFMA B-fragment load is then 64 lanes x 16B fully contiguous (1KB).

// ---------------- prep kernels ----------------

__global__ void k_gate(const float* __restrict__ gl, const float* __restrict__ traw,
                       float* __restrict__ gate) {
  int l = threadIdx.x;  // 64 threads
  float t = 1.f / (1.f + expf(-traw[0]));
  t = t * (1.f - 0.001f) + 0.001f;
  float v[4];
  float m = -3.4e38f;
  #pragma unroll
  for (int i = 0; i < 4; ++i) { v[i] = gl[l + i * 64] / t; m = fmaxf(m, v[i]); }
  #pragma unroll
  for (int s = 1; s < 64; s <<= 1) m = fmaxf(m, __shfl_xor(m, s));
  float sum = 0.f;
  #pragma unroll
  for (int i = 0; i < 4; ++i) { v[i] = expf(v[i] - m); sum += v[i]; }
  #pragma unroll
  for (int s = 1; s < 64; s <<= 1) sum += __shfl_xor(sum, s);
  #pragma unroll
  for (int i = 0; i < 4; ++i) gate[l + i * 64] = v[i] / sum;
}

// entmax15 over each row k of adj_logits; writes E[k][j]*gate[j] into egF at (col=j, kk=k)
__global__ void k_adj(const float* __restrict__ adj, const float* __restrict__ gate,
                      u16* __restrict__ egF) {
  int k = blockIdx.x, l = threadIdx.x;  // 256 blocks x 64 threads
  float z[4];
  float m = -3.4e38f;
  #pragma unroll
  for (int i = 0; i < 4; ++i) { z[i] = adj[(size_t)k * P + l + i * 64] * 0.5f; m = fmaxf(m, z[i]); }
  #pragma unroll
  for (int s = 1; s < 64; s <<= 1) m = fmaxf(m, __shfl_xor(m, s));
  float lo = m - 1.f, hi = m;
  for (int it = 0; it < 26; ++it) {
    float tau = 0.5f * (lo + hi), s = 0.f;
    #pragma unroll
    for (int i = 0; i < 4; ++i) { float d = z[i] - tau; s += (d > 0.f) ? d * d : 0.f; }
    #pragma unroll
    for (int sh = 1; sh < 64; sh <<= 1) s += __shfl_xor(s, sh);
    if (s >= 1.f) lo = tau; else hi = tau;
  }
  float tau = 0.5f * (lo + hi);
  int ss = k >> 5, g = (k >> 3) & 3, e = k & 7;
  #pragma unroll
  for (int i = 0; i < 4; ++i) {
    int j = l + i * 64;
    float d = z[i] - tau;
    float p = (d > 0.f) ? d * d : 0.f;
    int tt = j >> 4, lr = j & 15;
    egF[(size_t)(((ss * 16 + tt) * 64) + g * 16 + lr) * 8 + e] = f2bf(p * gate[j]);
  }
}

// proto -> pbF (GEMM1 B: col=p, k=d) and ptF (GEMM3 B: col=d, k=p); pnorm[p] = ||proto_p||^2
__global__ void k_proto(const float* __restrict__ proto, u16* __restrict__ pbF,
                        u16* __restrict__ ptF, float* __restrict__ pnorm) {
  int p = blockIdx.x, t = threadIdx.x;  // 256 blocks x 256 threads
  float s = 0.f;
  int ssp = (p >> 5) & 7, gp = (p >> 3) & 3, ep = p & 7;   // p as k-index (GEMM3)
  int ttp = p >> 4, lrp = p & 15;                          // p as col   (GEMM1)
  for (int d = t; d < D; d += 256) {
    float v = proto[(size_t)p * D + d];
    s += v * v;
    u16 u = f2bf(v);
    { // GEMM1: tile from col p, step from k=d
      int ss = d >> 5, g = (d >> 3) & 3, e = d & 7;
      pbF[(size_t)(((ss * 16 + ttp) * 64) + g * 16 + lrp) * 8 + e] = u;
    }
    { // GEMM3: [half][s][t16][lane][8], col=d, k=p
      int hf = d >> 8, tt = (d >> 4) & 15, lr = d & 15;
      ptF[(size_t)(((((hf * 8 + ssp) * 16) + tt) * 64) + gp * 16 + lr) * 8 + ep] = u;
    }
  }
  #pragma unroll
  for (int sh = 1; sh < 64; sh <<= 1) s += __shfl_xor(s, sh);
  __shared__ float red[4];
  if ((t & 63) == 0) red[t >> 6] = s;
  __syncthreads();
  if (t == 0) pnorm[p] = red[0] + red[1] + red[2] + red[3];
}

// ---------------- fused main kernel (zero barriers, wave-private LDS stripes) ----------------

__global__ __launch_bounds__(256, 4)
void k_main(const float* __restrict__ x, const u16* __restrict__ pbF,
            const u16* __restrict__ ptF, const u16* __restrict__ egF,
            const float* __restrict__ pnorm,
            float* __restrict__ out_blend, float* __restrict__ out_gated) {
  __shared__ __align__(16) u16 wbuf[BM][WS];   // 33792 B: entmax weights -> gated (bf16)

  int tid  = threadIdx.x;
  int brow = blockIdx.x * BM;

  int l    = tid & 63;
  int wv   = tid >> 6;        // wave id, 4 waves x 16-row stripes
  int r0   = wv * 16;
  int lrow = l & 15;
  int lk   = (l >> 4) * 8;    // k-offset within 32-wide K-step
  int lr4  = (l >> 4) * 4;    // row offset of this lane's acc quadrant

  // prototype norms for this lane's 16 output cols (issued early, L2-resident)
  float pn[16];
  #pragma unroll
  for (int c = 0; c < 16; ++c) pn[c] = pnorm[c * 16 + lrow];

  // ---- GEMM1: dot[64][256] = x_bf16 @ proto^T ; A streamed from global w/ prefetch ----
  f32x4 acc[16];
  #pragma unroll
  for (int c = 0; c < 16; ++c) acc[c] = {0.f, 0.f, 0.f, 0.f};

  const float* xrow = x + (size_t)(brow + r0 + lrow) * D + lk;
  const u16*   pbB  = pbF + (size_t)l * 8;
  float ssq = 0.f;

  float4 v0 = *(const float4*)(xrow);
  float4 v1 = *(const float4*)(xrow + 4);
  #pragma unroll 1
  for (int s = 0; s < 16; ++s) {
    float4 c0 = v0, c1 = v1;
    if (s < 15) {  // wave-uniform branch: prefetch next K-step's x chunk
      v0 = *(const float4*)(xrow + s * 32 + 32);
      v1 = *(const float4*)(xrow + s * 32 + 36);
    }
    ssq += c0.x * c0.x + c0.y * c0.y + c0.z * c0.z + c0.w * c0.w;
    ssq += c1.x * c1.x + c1.y * c1.y + c1.z * c1.z + c1.w * c1.w;
    union { bf16x8 v; uint32_t u[4]; } a;
    a.u[0] = (uint32_t)f2bf(c0.x) | ((uint32_t)f2bf(c0.y) << 16);
    a.u[1] = (uint32_t)f2bf(c0.z) | ((uint32_t)f2bf(c0.w) << 16);
    a.u[2] = (uint32_t)f2bf(c1.x) | ((uint32_t)f2bf(c1.y) << 16);
    a.u[3] = (uint32_t)f2bf(c1.z) | ((uint32_t)f2bf(c1.w) << 16);
    #pragma unroll
    for (int c = 0; c < 16; ++c) {
      bf16x8 b = *(const bf16x8*)(pbB + (size_t)(s * 16 + c) * 512);
      acc[c] = __builtin_amdgcn_mfma_f32_16x16x32_bf16(a.v, b, acc[c], 0, 0, 0);
    }
  }

  // full row ssq: union over the 4 lk-groups holding the same row
  ssq += __shfl_xor(ssq, 16);
  ssq += __shfl_xor(ssq, 32);
  float xnj[4];
  #pragma unroll
  for (int j = 0; j < 4; ++j) xnj[j] = __shfl(ssq, lr4 + j);

  // ---- z = -0.5*sqrt(clip(xn - 2*dot + pn, 0)) in place ----
  #pragma unroll
  for (int c = 0; c < 16; ++c) {
    #pragma unroll
    for (int j = 0; j < 4; ++j) {
      float sq = xnj[j] - 2.f * acc[c][j] + pn[c];
      acc[c][j] = -0.5f * sqrtf(fmaxf(sq, 0.f));
    }
  }

  // ---- entmax15: bisection fully in registers (4 rows/lane, reduce over 16-lane group) ----
  float mj[4] = {-3.4e38f, -3.4e38f, -3.4e38f, -3.4e38f};
  #pragma unroll
  for (int c = 0; c < 16; ++c) {
    #pragma unroll
    for (int j = 0; j < 4; ++j) mj[j] = fmaxf(mj[j], acc[c][j]);
  }
  #pragma unroll
  for (int j = 0; j < 4; ++j) {
    mj[j] = fmaxf(mj[j], __shfl_xor(mj[j], 1));
    mj[j] = fmaxf(mj[j], __shfl_xor(mj[j], 2));
    mj[j] = fmaxf(mj[j], __shfl_xor(mj[j], 4));
    mj[j] = fmaxf(mj[j], __shfl_xor(mj[j], 8));
  }
  float lo[4], hi[4];
  #pragma unroll
  for (int j = 0; j < 4; ++j) { lo[j] = mj[j] - 1.f; hi[j] = mj[j]; }

  for (int it = 0; it < 18; ++it) {
    float tau[4], s[4];
    #pragma unroll
    for (int j = 0; j < 4; ++j) { tau[j] = 0.5f * (lo[j] + hi[j]); s[j] = 0.f; }
    #pragma unroll
    for (int c = 0; c < 16; ++c) {
      #pragma unroll
      for (int j = 0; j < 4; ++j) {
        float d = fmaxf(acc[c][j] - tau[j], 0.f);
        s[j] = fmaf(d, d, s[j]);
      }
    }
    #pragma unroll
    for (int j = 0; j < 4; ++j) {
      s[j] += __shfl_xor(s[j], 1);
      s[j] += __shfl_xor(s[j], 2);
      s[j] += __shfl_xor(s[j], 4);
      s[j] += __shfl_xor(s[j], 8);
      bool ge = (s[j] >= 1.f);
      lo[j] = ge ? tau[j] : lo[j];
      hi[j] = ge ? hi[j] : tau[j];
    }
  }

  // ---- weights -> bf16 -> LDS (wave-private stripe; layout transpose for A-frags) ----
  {
    float tau[4];
    #pragma unroll
    for (int j = 0; j < 4; ++j) tau[j] = 0.5f * (lo[j] + hi[j]);
    #pragma unroll
    for (int c = 0; c < 16; ++c) {
      #pragma unroll
      for (int j = 0; j < 4; ++j) {
        float d = fmaxf(acc[c][j] - tau[j], 0.f);
        wbuf[r0 + lr4 + j][c * 16 + lrow] = f2bf(d * d);
      }
    }
  }

  // ---- GEMM2: routed_g[64][256] = w @ E_g ----
  f32x4 acc2[16];
  #pragma unroll
  for (int c = 0; c < 16; ++c) acc2[c] = {0.f, 0.f, 0.f, 0.f};

  const u16* egB = egF + (size_t)l * 8;
  #pragma unroll 1
  for (int s = 0; s < 8; ++s) {
    bf16x8 a = *(const bf16x8*)&wbuf[r0 + lrow][s * 32 + lk];
    #pragma unroll
    for (int c = 0; c < 16; ++c) {
      bf16x8 b = *(const bf16x8*)(egB + (size_t)(s * 16 + c) * 512);
      acc2[c] = __builtin_amdgcn_mfma_f32_16x16x32_bf16(a, b, acc2[c], 0, 0, 0);
    }
  }

  // ---- row-normalize: gated = routed_g / (rowsum + 1e-8) ----
  float part[4] = {0.f, 0.f, 0.f, 0.f};
  #pragma unroll
  for (int c = 0; c < 16; ++c) {
    #pragma unroll
    for (int j = 0; j < 4; ++j) part[j] += acc2[c][j];
  }
  #pragma unroll
  for (int j = 0; j < 4; ++j) {
    part[j] += __shfl_xor(part[j], 1);
    part[j] += __shfl_xor(part[j], 2);
    part[j] += __shfl_xor(part[j], 4);
    part[j] += __shfl_xor(part[j], 8);
    part[j] = 1.f / (part[j] + 1e-8f);
  }

  #pragma unroll
  for (int c = 0; c < 16; ++c) {
    int col = c * 16 + lrow;
    #pragma unroll
    for (int j = 0; j < 4; ++j) {
      int row = r0 + lr4 + j;
      float g = acc2[c][j] * part[j];
      out_gated[(size_t)(brow + row) * P + col] = g;
      wbuf[row][col] = f2bf(g);   // same wave-private stripe; w is dead
    }
  }

  // ---- GEMM3: blended[64][512] = gated @ proto (two 256-col halves) ----
  #pragma unroll 1
  for (int half = 0; half < 2; ++half) {
    f32x4 acc3[16];
    #pragma unroll
    for (int c = 0; c < 16; ++c) acc3[c] = {0.f, 0.f, 0.f, 0.f};
    const u16* ptB = ptF + (size_t)half * 8 * 16 * 512 + (size_t)l * 8;
    #pragma unroll 1
    for (int s = 0; s < 8; ++s) {
      bf16x8 a = *(const bf16x8*)&wbuf[r0 + lrow][s * 32 + lk];
      #pragma unroll
      for (int c = 0; c < 16; ++c) {
        bf16x8 b = *(const bf16x8*)(ptB + (size_t)(s * 16 + c) * 512);
        acc3[c] = __builtin_amdgcn_mfma_f32_16x16x32_bf16(a, b, acc3[c], 0, 0, 0);
      }
    }
    #pragma unroll
    for (int c = 0; c < 16; ++c) {
      int dcol = half * 256 + c * 16 + lrow;
      #pragma unroll
      for (int j = 0; j < 4; ++j) {
        int row = r0 + lr4 + j;
        out_blend[(size_t)(brow + row) * D + dcol] = acc3[c][j];
      }
    }
  }
}

// ---------------- launcher ----------------

extern "C" void kernel_launch(void* const* d_in, const int* in_sizes, int n_in,
                              void* d_out, int out_size, void* d_ws, size_t ws_size,
                              hipStream_t stream) {
  const float* x     = (const float*)d_in[0];
  const float* proto = (const float*)d_in[1];
  const float* adj   = (const float*)d_in[2];
  const float* gl    = (const float*)d_in[3];
  const float* traw  = (const float*)d_in[4];
  int N = in_sizes[0] / D;  // 65536

  u16*   pbF   = (u16*)d_ws;                  // [16][16][64][8] bf16  GEMM1 B (256 KB)
  u16*   ptF   = pbF + (size_t)P * D;         // [2][8][16][64][8]     GEMM3 B (256 KB)
  u16*   egF   = ptF + (size_t)D * P;         // [8][16][64][8]        GEMM2 B (128 KB)
  float* pnorm = (float*)(egF + (size_t)P * P);
  float* gate  = pnorm + P;

  float* out_blend = (float*)d_out;
  float* out_gated = out_blend + (size_t)N * D;

  k_gate<<<1, 64, 0, stream>>>(gl, traw, gate);
  k_proto<<<P, 256, 0, stream>>>(proto, pbF, ptF, pnorm);
  k_adj<<<P, 64, 0, stream>>>(adj, gate, egF);
  k_main<<<N / BM, 256, 0, stream>>>(x, pbF, ptF, egF, pnorm, out_blend, out_gated);
}